// Round 2
// baseline (1393.973 us; speedup 1.0000x reference)
//
#include <hip/hip_runtime.h>
#include <hip/hip_bf16.h>
#include <cstddef>

#define E_EDGES 1000000
#define N_ATOMS_C 100000
#define NC 256
#define EPS_C 1e-5f
#define INV_SQRT2 0.7071067811865476f

// ---------- bf16 helpers (raw ushort, RNE) ----------
__device__ __forceinline__ unsigned short f2bf(float x) {
    unsigned int u = __float_as_uint(x);
    unsigned int r = (u + 0x7FFFu + ((u >> 16) & 1u)) >> 16;
    return (unsigned short)r;
}
__device__ __forceinline__ float bf2f(unsigned short s) {
    return __uint_as_float(((unsigned int)s) << 16);
}

typedef __attribute__((ext_vector_type(8))) short bf16x8;   // 8 bf16 = 4 VGPR
typedef __attribute__((ext_vector_type(4))) float f32x4;
typedef __attribute__((ext_vector_type(8))) unsigned short ushort8_t;

// ---------- zero the stats region ----------
__global__ void k_zero(float* __restrict__ p, int n) {
    int i = blockIdx.x * 256 + threadIdx.x;
    if (i < n) p[i] = 0.f;
}

// ---------- per-crystal edge counts via binary search (cidx sorted) ----------
__device__ __forceinline__ int lowb(const int* __restrict__ c, int n, int key) {
    int lo = 0, hi = n;
    while (lo < hi) { int m = (lo + hi) >> 1; if (c[m] < key) lo = m + 1; else hi = m; }
    return lo;
}
__global__ void k_bounds(const int* __restrict__ cidx, float* __restrict__ cntb) {
    int cr = threadIdx.x;           // 0..255
    int a = lowb(cidx, E_EDGES, cr);
    int b = lowb(cidx, E_EDGES, cr + 1);
    cntb[cr] = (float)(b - a);
}

// ---------- prep: W_full (128x128 f32, [k][f]) -> Wt (bf16, [f][k]) ----------
__global__ void k_prepw(const float* __restrict__ Wf, unsigned short* __restrict__ Wt) {
    int idx = blockIdx.x * 256 + threadIdx.x;   // 0..16383
    int f = idx >> 7, k = idx & 127;
    Wt[f * 128 + k] = f2bf(Wf[(size_t)k * 128 + f]);
}

// ---------- prep: per-(crystal,feature) scale/bias for norm2 ----------
// x_norm = xv*scale + bias;  scale = rstd*gamma, bias = beta - mean*rstd*gamma
__global__ void k_prep2(const float* __restrict__ sum2, const float* __restrict__ sq2,
                        const float* __restrict__ cntb,
                        const float* __restrict__ gamma2, const float* __restrict__ beta2,
                        float2* __restrict__ sb2)
{
    int idx = blockIdx.x * 256 + threadIdx.x;   // 0..16383
    if (idx >= NC * 64) return;
    int c = idx >> 6, f = idx & 63;
    float rc = 1.f / fmaxf(cntb[c], 1.f);
    float m = sum2[idx] * rc;
    float v = sq2[idx] * rc - m * m;
    float s = rsqrtf(v + EPS_C) * gamma2[f];
    sb2[idx] = make_float2(s, beta2[f] - m * s);
}

// ---------- K1: gated = [diff||edge] @ W_full via bf16 MFMA, + stats1 ----------
// grid: 15625 tiles. block 256 (4 waves). tile = 64 edges x 128 feats.
// wave w owns output cols [w*32, w*32+32). B lives in VGPRs (loaded once).
#define TE 64
#define SAW 136   // A-tile row stride in bf16 (272 B: +16B pad -> <=2-way bank alias)
__global__ __launch_bounds__(256, 4) void k_gemm1(
    const float* __restrict__ atom, const float* __restrict__ edg,
    const int* __restrict__ nbr, const int* __restrict__ cidx,
    const unsigned short* __restrict__ Wt,
    unsigned short* __restrict__ gated,
    float* __restrict__ sum1, float* __restrict__ sq1)
{
    __shared__ __align__(16) unsigned short As[TE * SAW];   // 17.4 KB
    __shared__ int  cl[TE];
    __shared__ int2 i01[TE];

    const int e0 = blockIdx.x * TE;
    const int t  = threadIdx.x;
    const int w  = t >> 6, l = t & 63;
    const int lr = l & 15, lg = l >> 4;     // frag row/col, k-group

    if (t < TE)            cl[t]       = cidx[e0 + t];
    else if (t < 2 * TE)   i01[t - TE] = ((const int2*)nbr)[e0 + t - TE];

    // B fragments straight from global into VGPRs (W is L2/L3-hot, 32 KB total).
    // B[k][col]: lane holds k = ks*32 + lg*8 + j, col = w*32 + cf*16 + lr.
    bf16x8 bfr[4][2];
    #pragma unroll
    for (int ks = 0; ks < 4; ks++)
        #pragma unroll
        for (int cf = 0; cf < 2; cf++) {
            int col = w * 32 + cf * 16 + lr;
            bfr[ks][cf] = *(const bf16x8*)(Wt + (size_t)col * 128 + ks * 32 + lg * 8);
        }
    __syncthreads();

    // stage A tile: k 0..63 = diff (gather), k 64..127 = edge. fp32 -> bf16.
    #pragma unroll
    for (int it = 0; it < 8; it++) {
        int idx = t + it * 256;
        int e = idx >> 5, q = idx & 31;
        float4 v;
        if (q < 16) {
            int2 ii = i01[e];
            float4 a1 = *(const float4*)(atom + (size_t)ii.y * 64 + q * 4);
            float4 a0 = *(const float4*)(atom + (size_t)ii.x * 64 + q * 4);
            v = make_float4(a1.x - a0.x, a1.y - a0.y, a1.z - a0.z, a1.w - a0.w);
        } else {
            v = *(const float4*)(edg + (size_t)(e0 + e) * 64 + (q - 16) * 4);
        }
        ushort4 p;
        p.x = f2bf(v.x); p.y = f2bf(v.y); p.z = f2bf(v.z); p.w = f2bf(v.w);
        *(ushort4*)(As + e * SAW + q * 4) = p;
    }
    __syncthreads();

    // MFMA: acc[rf][cf] covers edges rf*16+[0,16), cols w*32+cf*16+[0,16)
    f32x4 acc[4][2];
    #pragma unroll
    for (int rf = 0; rf < 4; rf++)
        #pragma unroll
        for (int cf = 0; cf < 2; cf++)
            acc[rf][cf] = (f32x4){0.f, 0.f, 0.f, 0.f};

    #pragma unroll
    for (int ks = 0; ks < 4; ks++) {
        bf16x8 a[4];
        #pragma unroll
        for (int rf = 0; rf < 4; rf++)
            a[rf] = *(const bf16x8*)(As + (rf * 16 + lr) * SAW + ks * 32 + lg * 8);
        #pragma unroll
        for (int rf = 0; rf < 4; rf++)
            #pragma unroll
            for (int cf = 0; cf < 2; cf++)
                acc[rf][cf] = __builtin_amdgcn_mfma_f32_16x16x32_bf16(
                    a[rf], bfr[ks][cf], acc[rf][cf], 0, 0, 0);
    }

    // write gated bf16. C/D layout: col = lane&15, row = (lane>>4)*4 + r.
    #pragma unroll
    for (int rf = 0; rf < 4; rf++)
        #pragma unroll
        for (int cf = 0; cf < 2; cf++) {
            int col = w * 32 + cf * 16 + lr;
            #pragma unroll
            for (int r = 0; r < 4; r++) {
                int ge = e0 + rf * 16 + lg * 4 + r;
                gated[(size_t)ge * 128 + col] = f2bf(acc[rf][cf][r]);
            }
        }

    // stats1: per-feature sums are lane-local (fixed col per lane).
    const bool pure = (cl[0] == cl[TE - 1]);    // cidx sorted
    if (pure) {
        int c = cl[0];
        #pragma unroll
        for (int cf = 0; cf < 2; cf++) {
            float s = 0.f, q = 0.f;
            #pragma unroll
            for (int rf = 0; rf < 4; rf++)
                #pragma unroll
                for (int r = 0; r < 4; r++) {
                    float v = acc[rf][cf][r];
                    s += v; q += v * v;
                }
            s += __shfl_xor(s, 16); s += __shfl_xor(s, 32);
            q += __shfl_xor(q, 16); q += __shfl_xor(q, 32);
            if (lg == 0) {
                int col = w * 32 + cf * 16 + lr;
                atomicAdd(&sum1[c * 128 + col], s);
                atomicAdd(&sq1 [c * 128 + col], q);
            }
        }
    } else {
        #pragma unroll
        for (int cf = 0; cf < 2; cf++) {
            int col = w * 32 + cf * 16 + lr;
            float s = 0.f, q = 0.f;
            int cp = cl[lg * 4];
            #pragma unroll
            for (int rf = 0; rf < 4; rf++)
                #pragma unroll
                for (int r = 0; r < 4; r++) {
                    int row = rf * 16 + lg * 4 + r;
                    int cc = cl[row];
                    if (cc != cp) {
                        atomicAdd(&sum1[cp * 128 + col], s);
                        atomicAdd(&sq1 [cp * 128 + col], q);
                        s = 0.f; q = 0.f; cp = cc;
                    }
                    float v = acc[rf][cf][r];
                    s += v; q += v * v;
                }
            atomicAdd(&sum1[cp * 128 + col], s);
            atomicAdd(&sq1 [cp * 128 + col], q);
        }
    }
}

// ---------- K2: normalize1 + tanh gate -> mid, + stats2 ----------
// wave per edge (lane = feature), 4 waves/block, 64 edges per wave
__global__ __launch_bounds__(256) void k_gate(
    const unsigned short* __restrict__ gated, const int* __restrict__ cidx,
    const float* __restrict__ sum1, const float* __restrict__ sq1,
    const float* __restrict__ cntb,
    const float* __restrict__ gamma1, const float* __restrict__ beta1,
    const float* __restrict__ Wm,
    unsigned short* __restrict__ mid,
    float* __restrict__ sum2, float* __restrict__ sq2)
{
    const int w = threadIdx.x >> 6, f = threadIdx.x & 63;
    const int base = blockIdx.x * 256 + w * 64;
    const float g1c = gamma1[f], b1c = beta1[f];
    const float g1f = gamma1[64 + f], b1f = beta1[64 + f];
    const float wm = Wm[f];

    int cprev = -1, crun = -1;
    float m_c = 0.f, r_c = 0.f, m_f = 0.f, r_f = 0.f;
    float s_acc = 0.f, q_acc = 0.f;

    for (int it = 0; it < 64; it++) {
        int e = base + it;
        if (e >= E_EDGES) break;
        int c = cidx[e];                 // wave-uniform
        if (c != cprev) {
            float rc = 1.f / fmaxf(cntb[c], 1.f);
            float m1 = sum1[c * 128 + f] * rc;
            float v1 = sq1[c * 128 + f] * rc - m1 * m1;
            m_c = m1; r_c = rsqrtf(v1 + EPS_C);
            float m2 = sum1[c * 128 + 64 + f] * rc;
            float v2 = sq1[c * 128 + 64 + f] * rc - m2 * m2;
            m_f = m2; r_f = rsqrtf(v2 + EPS_C);
            cprev = c;
        }
        float core = bf2f(gated[(size_t)e * 128 + f]);
        float filt = bf2f(gated[(size_t)e * 128 + 64 + f]);
        float cn = (core - m_c) * r_c * g1c + b1c;
        float fn = (filt - m_f) * r_f * g1f + b1f;
        float p = fn * wm;
        #pragma unroll
        for (int o = 32; o > 0; o >>= 1) p += __shfl_xor(p, o, 64);
        float th = tanhf(p);
        float v = th * fmaxf(cn, 0.f);
        mid[(size_t)e * 64 + f] = f2bf(v);
        if (c != crun) {
            if (crun >= 0) {
                atomicAdd(&sum2[crun * 64 + f], s_acc);
                atomicAdd(&sq2 [crun * 64 + f], q_acc);
            }
            s_acc = 0.f; q_acc = 0.f; crun = c;
        }
        s_acc += v; q_acc += v * v;
    }
    if (crun >= 0) {
        atomicAdd(&sum2[crun * 64 + f], s_acc);
        atomicAdd(&sq2 [crun * 64 + f], q_acc);
    }
}

// ---------- K3: normalize2 (precomputed scale/bias) + 2 residual MLPs + relu ----------
// thread per edge; x[64],h[32] in VGPRs; weights wave-uniform -> scalar loads.
// __launch_bounds__(256,2): VGPR cap 256 -> NO scratch spill (needs ~120 live).
__global__ __launch_bounds__(256, 2) void k_mlp(
    const unsigned short* __restrict__ mid, const int* __restrict__ cidx,
    const float* __restrict__ edg,
    const float2* __restrict__ sb2,
    const float* __restrict__ rW1, const float* __restrict__ rB1,
    const float* __restrict__ rW2, const float* __restrict__ rB2,
    float* __restrict__ out)
{
    int e = blockIdx.x * 256 + threadIdx.x;
    if (e >= E_EDGES) return;
    int c = cidx[e];

    float x[64];
    const unsigned short* mrow = mid + (size_t)e * 64;
    #pragma unroll
    for (int q = 0; q < 8; q++) {
        ushort8_t u = *(const ushort8_t*)(mrow + q * 8);
        #pragma unroll
        for (int j = 0; j < 8; j++) {
            int f = q * 8 + j;
            float2 sb = sb2[c * 64 + f];        // broadcast within wave (sorted cidx)
            x[f] = fmaf(bf2f((unsigned short)u[j]), sb.x, sb.y);
        }
    }
    #pragma unroll
    for (int i = 0; i < 2; i++) {
        float h[32];
        #pragma unroll
        for (int j = 0; j < 32; j++) h[j] = rB1[i * 32 + j];
        #pragma unroll
        for (int f = 0; f < 64; f++) {
            const float* wrow = rW1 + i * 2048 + f * 32;   // uniform -> s_load
            float xv = x[f];
            #pragma unroll
            for (int j = 0; j < 32; j++) h[j] = fmaf(xv, wrow[j], h[j]);
        }
        #pragma unroll
        for (int j = 0; j < 32; j++) h[j] = fmaxf(h[j], 0.f);
        #pragma unroll
        for (int f = 0; f < 64; f++) x[f] += rB2[i * 64 + f];
        #pragma unroll
        for (int j = 0; j < 32; j++) {
            const float* wrow = rW2 + i * 2048 + j * 64;   // uniform -> s_load
            float hv = h[j];
            #pragma unroll
            for (int f = 0; f < 64; f++) x[f] = fmaf(hv, wrow[f], x[f]);
        }
    }
    const float* erow = edg + (size_t)e * 64;
    float* orow = out + (size_t)e * 64;
    #pragma unroll
    for (int q = 0; q < 16; q++) {
        float4 ev = *(const float4*)(erow + q * 4);
        float4 o;
        o.x = INV_SQRT2 * fmaxf(ev.x + x[q * 4 + 0], 0.f);
        o.y = INV_SQRT2 * fmaxf(ev.y + x[q * 4 + 1], 0.f);
        o.z = INV_SQRT2 * fmaxf(ev.z + x[q * 4 + 2], 0.f);
        o.w = INV_SQRT2 * fmaxf(ev.w + x[q * 4 + 3], 0.f);
        *(float4*)(orow + q * 4) = o;
    }
}

extern "C" void kernel_launch(void* const* d_in, const int* in_sizes, int n_in,
                              void* d_out, int out_size, void* d_ws, size_t ws_size,
                              hipStream_t stream)
{
    const float* atom   = (const float*)d_in[0];
    const float* edg    = (const float*)d_in[1];
    const int*   nbr    = (const int*)d_in[2];
    const int*   cidx   = (const int*)d_in[3];
    const float* Wf     = (const float*)d_in[4];
    const float* Wm     = (const float*)d_in[5];
    const float* gamma1 = (const float*)d_in[6];
    const float* beta1  = (const float*)d_in[7];
    const float* gamma2 = (const float*)d_in[8];
    const float* beta2  = (const float*)d_in[9];
    const float* rW1    = (const float*)d_in[10];
    const float* rB1    = (const float*)d_in[11];
    const float* rW2    = (const float*)d_in[12];
    const float* rB2    = (const float*)d_in[13];
    float* out = (float*)d_out;

    char* ws = (char*)d_ws;
    unsigned short* gated = (unsigned short*)ws;                               // E*128 bf16
    unsigned short* mid   = (unsigned short*)(ws + (size_t)E_EDGES * 128 * 2); // E*64 bf16
    float* stats = (float*)(ws + (size_t)E_EDGES * 128 * 2 + (size_t)E_EDGES * 64 * 2);
    float* sum1 = stats;                 // 256*128
    float* sq1  = sum1 + 256 * 128;      // 256*128
    float* sum2 = sq1 + 256 * 128;       // 256*64
    float* sq2  = sum2 + 256 * 64;       // 256*64
    float* cntb = sq2 + 256 * 64;        // 256
    unsigned short* Wt = (unsigned short*)(cntb + 256);   // 128*128 bf16
    float2* sb2 = (float2*)(Wt + 128 * 128);              // 256*64 float2 (8B-aligned)

    const int nstat = 2 * 256 * 128 + 2 * 256 * 64;
    k_zero<<<(nstat + 255) / 256, 256, 0, stream>>>(sum1, nstat);
    k_bounds<<<1, 256, 0, stream>>>(cidx, cntb);
    k_prepw<<<64, 256, 0, stream>>>(Wf, Wt);
    k_gemm1<<<E_EDGES / TE, 256, 0, stream>>>(atom, edg, nbr, cidx, Wt, gated, sum1, sq1);
    k_gate<<<(E_EDGES + 255) / 256, 256, 0, stream>>>(gated, cidx, sum1, sq1, cntb,
                                                      gamma1, beta1, Wm, mid, sum2, sq2);
    k_prep2<<<64, 256, 0, stream>>>(sum2, sq2, cntb, gamma2, beta2, sb2);
    k_mlp<<<(E_EDGES + 255) / 256, 256, 0, stream>>>(mid, cidx, edg, sb2,
                                                     rW1, rB1, rW2, rB2, out);
}

// Round 3
// 978.037 us; speedup vs baseline: 1.4253x; 1.4253x over previous
//
#include <hip/hip_runtime.h>
#include <hip/hip_bf16.h>
#include <cstddef>

#define E_EDGES 1000000
#define N_ATOMS_C 100000
#define NC 256
#define EPS_C 1e-5f
#define INV_SQRT2 0.7071067811865476f

// ---------- bf16 helpers (raw ushort, RNE) ----------
__device__ __forceinline__ unsigned short f2bf(float x) {
    unsigned int u = __float_as_uint(x);
    unsigned int r = (u + 0x7FFFu + ((u >> 16) & 1u)) >> 16;
    return (unsigned short)r;
}
__device__ __forceinline__ float bf2f(unsigned short s) {
    return __uint_as_float(((unsigned int)s) << 16);
}

typedef __attribute__((ext_vector_type(8))) short bf16x8;   // 8 bf16 = 4 VGPR
typedef __attribute__((ext_vector_type(4))) float f32x4;
typedef __attribute__((ext_vector_type(8))) unsigned short ushort8_t;

// ---------- zero the stats region ----------
__global__ void k_zero(float* __restrict__ p, int n) {
    int i = blockIdx.x * 256 + threadIdx.x;
    if (i < n) p[i] = 0.f;
}

// ---------- per-crystal edge counts via binary search (cidx sorted) ----------
__device__ __forceinline__ int lowb(const int* __restrict__ c, int n, int key) {
    int lo = 0, hi = n;
    while (lo < hi) { int m = (lo + hi) >> 1; if (c[m] < key) lo = m + 1; else hi = m; }
    return lo;
}
__global__ void k_bounds(const int* __restrict__ cidx, float* __restrict__ cntb) {
    int cr = threadIdx.x;           // 0..255
    int a = lowb(cidx, E_EDGES, cr);
    int b = lowb(cidx, E_EDGES, cr + 1);
    cntb[cr] = (float)(b - a);
}

// ---------- prep: W_full (128x128 f32, [k][f]) -> Wt (bf16, [f][k]) ----------
__global__ void k_prepw(const float* __restrict__ Wf, unsigned short* __restrict__ Wt) {
    int idx = blockIdx.x * 256 + threadIdx.x;   // 0..16383
    int f = idx >> 7, k = idx & 127;
    Wt[f * 128 + k] = f2bf(Wf[(size_t)k * 128 + f]);
}

// ---------- prep: residual-MLP weights -> bf16 fragment layouts ----------
// W1t[i][j][f] = rW1[i][f][j]   (B-frag for x@W1:  col=j (32), k=f (64))
// W2t[i][f][j] = rW2[i][j][f]   (B-frag for h@W2:  col=f (64), k=j (32))
__global__ void k_prepr(const float* __restrict__ rW1, const float* __restrict__ rW2,
                        unsigned short* __restrict__ W1t, unsigned short* __restrict__ W2t)
{
    int idx = blockIdx.x * 256 + threadIdx.x;   // 0..4095
    {
        int i = idx >> 11, j = (idx >> 6) & 31, f = idx & 63;
        W1t[idx] = f2bf(rW1[i * 2048 + f * 32 + j]);
    }
    {
        int i = idx >> 11, f = (idx >> 5) & 63, j = idx & 31;
        W2t[idx] = f2bf(rW2[i * 2048 + j * 64 + f]);
    }
}

// ---------- prep: per-(crystal,feature) scale/bias for norm2 ----------
__global__ void k_prep2(const float* __restrict__ sum2, const float* __restrict__ sq2,
                        const float* __restrict__ cntb,
                        const float* __restrict__ gamma2, const float* __restrict__ beta2,
                        float2* __restrict__ sb2)
{
    int idx = blockIdx.x * 256 + threadIdx.x;   // 0..16383
    if (idx >= NC * 64) return;
    int c = idx >> 6, f = idx & 63;
    float rc = 1.f / fmaxf(cntb[c], 1.f);
    float m = sum2[idx] * rc;
    float v = sq2[idx] * rc - m * m;
    float s = rsqrtf(v + EPS_C) * gamma2[f];
    sb2[idx] = make_float2(s, beta2[f] - m * s);
}

// ---------- K1: gated = [diff||edge] @ W_full via bf16 MFMA, + stats1 ----------
#define TE 64
#define SAW 136   // A-tile row stride in bf16
__global__ __launch_bounds__(256, 4) void k_gemm1(
    const float* __restrict__ atom, const float* __restrict__ edg,
    const int* __restrict__ nbr, const int* __restrict__ cidx,
    const unsigned short* __restrict__ Wt,
    unsigned short* __restrict__ gated,
    float* __restrict__ sum1, float* __restrict__ sq1)
{
    __shared__ __align__(16) unsigned short As[TE * SAW];   // 17.4 KB
    __shared__ int  cl[TE];
    __shared__ int2 i01[TE];

    const int e0 = blockIdx.x * TE;
    const int t  = threadIdx.x;
    const int w  = t >> 6, l = t & 63;
    const int lr = l & 15, lg = l >> 4;

    if (t < TE)            cl[t]       = cidx[e0 + t];
    else if (t < 2 * TE)   i01[t - TE] = ((const int2*)nbr)[e0 + t - TE];

    bf16x8 bfr[4][2];
    #pragma unroll
    for (int ks = 0; ks < 4; ks++)
        #pragma unroll
        for (int cf = 0; cf < 2; cf++) {
            int col = w * 32 + cf * 16 + lr;
            bfr[ks][cf] = *(const bf16x8*)(Wt + (size_t)col * 128 + ks * 32 + lg * 8);
        }
    __syncthreads();

    #pragma unroll
    for (int it = 0; it < 8; it++) {
        int idx = t + it * 256;
        int e = idx >> 5, q = idx & 31;
        float4 v;
        if (q < 16) {
            int2 ii = i01[e];
            float4 a1 = *(const float4*)(atom + (size_t)ii.y * 64 + q * 4);
            float4 a0 = *(const float4*)(atom + (size_t)ii.x * 64 + q * 4);
            v = make_float4(a1.x - a0.x, a1.y - a0.y, a1.z - a0.z, a1.w - a0.w);
        } else {
            v = *(const float4*)(edg + (size_t)(e0 + e) * 64 + (q - 16) * 4);
        }
        ushort4 p;
        p.x = f2bf(v.x); p.y = f2bf(v.y); p.z = f2bf(v.z); p.w = f2bf(v.w);
        *(ushort4*)(As + e * SAW + q * 4) = p;
    }
    __syncthreads();

    f32x4 acc[4][2];
    #pragma unroll
    for (int rf = 0; rf < 4; rf++)
        #pragma unroll
        for (int cf = 0; cf < 2; cf++)
            acc[rf][cf] = (f32x4){0.f, 0.f, 0.f, 0.f};

    #pragma unroll
    for (int ks = 0; ks < 4; ks++) {
        bf16x8 a[4];
        #pragma unroll
        for (int rf = 0; rf < 4; rf++)
            a[rf] = *(const bf16x8*)(As + (rf * 16 + lr) * SAW + ks * 32 + lg * 8);
        #pragma unroll
        for (int rf = 0; rf < 4; rf++)
            #pragma unroll
            for (int cf = 0; cf < 2; cf++)
                acc[rf][cf] = __builtin_amdgcn_mfma_f32_16x16x32_bf16(
                    a[rf], bfr[ks][cf], acc[rf][cf], 0, 0, 0);
    }

    #pragma unroll
    for (int rf = 0; rf < 4; rf++)
        #pragma unroll
        for (int cf = 0; cf < 2; cf++) {
            int col = w * 32 + cf * 16 + lr;
            #pragma unroll
            for (int r = 0; r < 4; r++) {
                int ge = e0 + rf * 16 + lg * 4 + r;
                gated[(size_t)ge * 128 + col] = f2bf(acc[rf][cf][r]);
            }
        }

    const bool pure = (cl[0] == cl[TE - 1]);
    if (pure) {
        int c = cl[0];
        #pragma unroll
        for (int cf = 0; cf < 2; cf++) {
            float s = 0.f, q = 0.f;
            #pragma unroll
            for (int rf = 0; rf < 4; rf++)
                #pragma unroll
                for (int r = 0; r < 4; r++) {
                    float v = acc[rf][cf][r];
                    s += v; q += v * v;
                }
            s += __shfl_xor(s, 16); s += __shfl_xor(s, 32);
            q += __shfl_xor(q, 16); q += __shfl_xor(q, 32);
            if (lg == 0) {
                int col = w * 32 + cf * 16 + lr;
                atomicAdd(&sum1[c * 128 + col], s);
                atomicAdd(&sq1 [c * 128 + col], q);
            }
        }
    } else {
        #pragma unroll
        for (int cf = 0; cf < 2; cf++) {
            int col = w * 32 + cf * 16 + lr;
            float s = 0.f, q = 0.f;
            int cp = cl[lg * 4];
            #pragma unroll
            for (int rf = 0; rf < 4; rf++)
                #pragma unroll
                for (int r = 0; r < 4; r++) {
                    int row = rf * 16 + lg * 4 + r;
                    int cc = cl[row];
                    if (cc != cp) {
                        atomicAdd(&sum1[cp * 128 + col], s);
                        atomicAdd(&sq1 [cp * 128 + col], q);
                        s = 0.f; q = 0.f; cp = cc;
                    }
                    float v = acc[rf][cf][r];
                    s += v; q += v * v;
                }
            atomicAdd(&sum1[cp * 128 + col], s);
            atomicAdd(&sq1 [cp * 128 + col], q);
        }
    }
}

// ---------- K2: normalize1 + tanh gate -> mid, + stats2 ----------
__global__ __launch_bounds__(256) void k_gate(
    const unsigned short* __restrict__ gated, const int* __restrict__ cidx,
    const float* __restrict__ sum1, const float* __restrict__ sq1,
    const float* __restrict__ cntb,
    const float* __restrict__ gamma1, const float* __restrict__ beta1,
    const float* __restrict__ Wm,
    unsigned short* __restrict__ mid,
    float* __restrict__ sum2, float* __restrict__ sq2)
{
    const int w = threadIdx.x >> 6, f = threadIdx.x & 63;
    const int base = blockIdx.x * 256 + w * 64;
    const float g1c = gamma1[f], b1c = beta1[f];
    const float g1f = gamma1[64 + f], b1f = beta1[64 + f];
    const float wm = Wm[f];

    int cprev = -1, crun = -1;
    float m_c = 0.f, r_c = 0.f, m_f = 0.f, r_f = 0.f;
    float s_acc = 0.f, q_acc = 0.f;

    for (int it = 0; it < 64; it++) {
        int e = base + it;
        if (e >= E_EDGES) break;
        int c = cidx[e];
        if (c != cprev) {
            float rc = 1.f / fmaxf(cntb[c], 1.f);
            float m1 = sum1[c * 128 + f] * rc;
            float v1 = sq1[c * 128 + f] * rc - m1 * m1;
            m_c = m1; r_c = rsqrtf(v1 + EPS_C);
            float m2 = sum1[c * 128 + 64 + f] * rc;
            float v2 = sq1[c * 128 + 64 + f] * rc - m2 * m2;
            m_f = m2; r_f = rsqrtf(v2 + EPS_C);
            cprev = c;
        }
        float core = bf2f(gated[(size_t)e * 128 + f]);
        float filt = bf2f(gated[(size_t)e * 128 + 64 + f]);
        float cn = (core - m_c) * r_c * g1c + b1c;
        float fn = (filt - m_f) * r_f * g1f + b1f;
        float p = fn * wm;
        #pragma unroll
        for (int o = 32; o > 0; o >>= 1) p += __shfl_xor(p, o, 64);
        float th = tanhf(p);
        float v = th * fmaxf(cn, 0.f);
        mid[(size_t)e * 64 + f] = f2bf(v);
        if (c != crun) {
            if (crun >= 0) {
                atomicAdd(&sum2[crun * 64 + f], s_acc);
                atomicAdd(&sq2 [crun * 64 + f], q_acc);
            }
            s_acc = 0.f; q_acc = 0.f; crun = c;
        }
        s_acc += v; q_acc += v * v;
    }
    if (crun >= 0) {
        atomicAdd(&sum2[crun * 64 + f], s_acc);
        atomicAdd(&sq2 [crun * 64 + f], q_acc);
    }
}

// ---------- K3: norm2 + 2 residual MLPs via MFMA + final relu ----------
// tile = 64 edges, 4 waves; wave w owns edges w*16+[0,16).
// xr[4][4] fp32 C-layout (col=cf*16+lr, row=lg*4+r) is the residual base.
// No per-thread arrays with runtime indices -> no scratch.
#define SX 72   // Xs row stride (bf16): 144 B -> 16B-aligned rows, 2-way bank alias
#define SH 40   // Hs row stride (bf16): 80 B  -> 16B-aligned rows, 2-way bank alias
__global__ __launch_bounds__(256) void k_mlp(
    const unsigned short* __restrict__ mid, const int* __restrict__ cidx,
    const float* __restrict__ edg,
    const float2* __restrict__ sb2,
    const unsigned short* __restrict__ W1t, const unsigned short* __restrict__ W2t,
    const float* __restrict__ rB1, const float* __restrict__ rB2,
    float* __restrict__ out)
{
    __shared__ __align__(16) unsigned short Xs[TE * SX];   // 9.2 KB
    __shared__ __align__(16) unsigned short Hs[TE * SH];   // 5.1 KB

    const int e0 = blockIdx.x * TE;
    const int t  = threadIdx.x;
    const int w  = t >> 6, l = t & 63;
    const int lr = l & 15, lg = l >> 4;

    // ---- stage normalized x (bf16) into Xs: thread -> (edge t>>2, f-quarter t&3)
    {
        int e  = t >> 2;
        int f0 = (t & 3) * 16;
        int c  = cidx[e0 + e];
        const unsigned short* mrow = mid + (size_t)(e0 + e) * 64 + f0;
        ushort8_t u0 = *(const ushort8_t*)(mrow);
        ushort8_t u1 = *(const ushort8_t*)(mrow + 8);
        ushort8_t o0, o1;
        #pragma unroll
        for (int j = 0; j < 8; j++) {
            float2 sb = sb2[c * 64 + f0 + j];
            o0[j] = f2bf(fmaf(bf2f((unsigned short)u0[j]), sb.x, sb.y));
        }
        #pragma unroll
        for (int j = 0; j < 8; j++) {
            float2 sb = sb2[c * 64 + f0 + 8 + j];
            o1[j] = f2bf(fmaf(bf2f((unsigned short)u1[j]), sb.x, sb.y));
        }
        *(ushort8_t*)(Xs + e * SX + f0)     = o0;
        *(ushort8_t*)(Xs + e * SX + f0 + 8) = o1;
    }
    __syncthreads();
    // after this point all LDS rows touched by wave w are rows w*16+[0,16) only

    // ---- fp32 residual base in C-layout ----
    float xr[4][4];
    #pragma unroll
    for (int cf = 0; cf < 4; cf++)
        #pragma unroll
        for (int r = 0; r < 4; r++)
            xr[cf][r] = bf2f(Xs[(w * 16 + lg * 4 + r) * SX + cf * 16 + lr]);

    // ---- 2 residual layers ----
    #pragma unroll
    for (int i = 0; i < 2; i++) {
        // layer biases (per-lane col)
        float b1v0 = rB1[i * 32 + lr];
        float b1v1 = rB1[i * 32 + 16 + lr];
        float b2v[4];
        #pragma unroll
        for (int cf = 0; cf < 4; cf++) b2v[cf] = rB2[i * 64 + cf * 16 + lr];

        // A-frags of x (K=64: ks 0..1)
        bf16x8 a1[2];
        #pragma unroll
        for (int ks = 0; ks < 2; ks++)
            a1[ks] = *(const bf16x8*)(Xs + (w * 16 + lr) * SX + ks * 32 + lg * 8);

        // h = relu(x@W1 + b1): N=32 (cf 0..1), K=64
        f32x4 hacc[2];
        hacc[0] = (f32x4){0.f, 0.f, 0.f, 0.f};
        hacc[1] = (f32x4){0.f, 0.f, 0.f, 0.f};
        #pragma unroll
        for (int ks = 0; ks < 2; ks++)
            #pragma unroll
            for (int cf = 0; cf < 2; cf++) {
                bf16x8 b1f = *(const bf16x8*)(W1t + i * 2048 + (cf * 16 + lr) * 64 + ks * 32 + lg * 8);
                hacc[cf] = __builtin_amdgcn_mfma_f32_16x16x32_bf16(a1[ks], b1f, hacc[cf], 0, 0, 0);
            }

        // bias+relu, transpose h into Hs (wave-private rows)
        #pragma unroll
        for (int r = 0; r < 4; r++) {
            Hs[(w * 16 + lg * 4 + r) * SH + lr]      = f2bf(fmaxf(hacc[0][r] + b1v0, 0.f));
            Hs[(w * 16 + lg * 4 + r) * SH + 16 + lr] = f2bf(fmaxf(hacc[1][r] + b1v1, 0.f));
        }

        // x += h@W2 + b2: N=64 (cf 0..3), K=32
        bf16x8 a2 = *(const bf16x8*)(Hs + (w * 16 + lr) * SH + lg * 8);
        #pragma unroll
        for (int cf = 0; cf < 4; cf++) {
            bf16x8 b2fv = *(const bf16x8*)(W2t + i * 2048 + (cf * 16 + lr) * 32 + lg * 8);
            f32x4 xacc = __builtin_amdgcn_mfma_f32_16x16x32_bf16(
                a2, b2fv, (f32x4){0.f, 0.f, 0.f, 0.f}, 0, 0, 0);
            #pragma unroll
            for (int r = 0; r < 4; r++)
                xr[cf][r] += xacc[r] + b2v[cf];
        }

        // refresh Xs for the next layer's A-frags (wave-private rows)
        if (i == 0) {
            #pragma unroll
            for (int cf = 0; cf < 4; cf++)
                #pragma unroll
                for (int r = 0; r < 4; r++)
                    Xs[(w * 16 + lg * 4 + r) * SX + cf * 16 + lr] = f2bf(xr[cf][r]);
        }
    }

    // ---- epilogue: out = inv_sqrt2 * relu(edge + x) ----
    #pragma unroll
    for (int cf = 0; cf < 4; cf++)
        #pragma unroll
        for (int r = 0; r < 4; r++) {
            int ge = e0 + w * 16 + lg * 4 + r;
            int f  = cf * 16 + lr;
            float ev = edg[(size_t)ge * 64 + f];
            out[(size_t)ge * 64 + f] = INV_SQRT2 * fmaxf(ev + xr[cf][r], 0.f);
        }
}

extern "C" void kernel_launch(void* const* d_in, const int* in_sizes, int n_in,
                              void* d_out, int out_size, void* d_ws, size_t ws_size,
                              hipStream_t stream)
{
    const float* atom   = (const float*)d_in[0];
    const float* edg    = (const float*)d_in[1];
    const int*   nbr    = (const int*)d_in[2];
    const int*   cidx   = (const int*)d_in[3];
    const float* Wf     = (const float*)d_in[4];
    const float* Wm     = (const float*)d_in[5];
    const float* gamma1 = (const float*)d_in[6];
    const float* beta1  = (const float*)d_in[7];
    const float* gamma2 = (const float*)d_in[8];
    const float* beta2  = (const float*)d_in[9];
    const float* rW1    = (const float*)d_in[10];
    const float* rB1    = (const float*)d_in[11];
    const float* rW2    = (const float*)d_in[12];
    const float* rB2    = (const float*)d_in[13];
    float* out = (float*)d_out;

    char* ws = (char*)d_ws;
    unsigned short* gated = (unsigned short*)ws;                               // E*128 bf16
    unsigned short* mid   = (unsigned short*)(ws + (size_t)E_EDGES * 128 * 2); // E*64 bf16
    float* stats = (float*)(ws + (size_t)E_EDGES * 128 * 2 + (size_t)E_EDGES * 64 * 2);
    float* sum1 = stats;                 // 256*128
    float* sq1  = sum1 + 256 * 128;      // 256*128
    float* sum2 = sq1 + 256 * 128;       // 256*64
    float* sq2  = sum2 + 256 * 64;       // 256*64
    float* cntb = sq2 + 256 * 64;        // 256
    unsigned short* Wt  = (unsigned short*)(cntb + 256);   // 128*128 bf16
    float2* sb2 = (float2*)(Wt + 128 * 128);               // 256*64 float2
    unsigned short* W1t = (unsigned short*)(sb2 + 256 * 64); // 2*32*64 bf16
    unsigned short* W2t = W1t + 4096;                        // 2*64*32 bf16

    const int nstat = 2 * 256 * 128 + 2 * 256 * 64;
    k_zero<<<(nstat + 255) / 256, 256, 0, stream>>>(sum1, nstat);
    k_bounds<<<1, 256, 0, stream>>>(cidx, cntb);
    k_prepw<<<64, 256, 0, stream>>>(Wf, Wt);
    k_prepr<<<16, 256, 0, stream>>>(rW1, rW2, W1t, W2t);
    k_gemm1<<<E_EDGES / TE, 256, 0, stream>>>(atom, edg, nbr, cidx, Wt, gated, sum1, sq1);
    k_gate<<<(E_EDGES + 255) / 256, 256, 0, stream>>>(gated, cidx, sum1, sq1, cntb,
                                                      gamma1, beta1, Wm, mid, sum2, sq2);
    k_prep2<<<64, 256, 0, stream>>>(sum2, sq2, cntb, gamma2, beta2, sb2);
    k_mlp<<<E_EDGES / TE, 256, 0, stream>>>(mid, cidx, edg, sb2, W1t, W2t,
                                            rB1, rB2, out);
}